// Round 1
// baseline (2498.162 us; speedup 1.0000x reference)
//
#include <hip/hip_runtime.h>
#include <math.h>

// Problem constants (B=2, T=2048, C=2048, HQ=16, HKV=4, Dh=128, WIN=256)
#define BB   2
#define TT   2048
#define CC   2048
#define HQ_  16
#define HKV_ 4
#define DH   128
#define MM   (BB * TT)          // 4096 rows
#define KVC  (HKV_ * DH)        // 512
static __device__ __constant__ float EPSC = 1.1920929e-07f;

// ---------------------------------------------------------------------------
// Tiled fp32 GEMM: C[M,N] = A[M,K] @ W[K,N], all row-major.
// 128x128 tile, BK=8, 256 threads, 8x8 per-thread microtile.
// ---------------------------------------------------------------------------
__global__ __launch_bounds__(256)
void gemm_f32(const float* __restrict__ A, const float* __restrict__ W,
              float* __restrict__ Cmat, int M, int N, int K) {
    __shared__ float As[8][132];   // [k][m], padded
    __shared__ float Bs[8][132];   // [k][n], padded

    const int tid = threadIdx.x;
    const int bm = blockIdx.y * 128;
    const int bn = blockIdx.x * 128;
    const int tm = tid >> 4;        // 0..15
    const int tn = tid & 15;        // 0..15

    float acc[8][8];
#pragma unroll
    for (int i = 0; i < 8; ++i)
#pragma unroll
        for (int j = 0; j < 8; ++j) acc[i][j] = 0.f;

    // staging indices
    const int ar  = tid >> 1;          // 0..127 (row in A tile)
    const int ac4 = (tid & 1) * 4;     // 0 or 4 (k offset)
    const int bk  = tid >> 5;          // 0..7  (k row in W tile)
    const int bn4 = (tid & 31) * 4;    // 0..124 (n offset)

    for (int kt = 0; kt < K; kt += 8) {
        float4 av = *(const float4*)&A[(size_t)(bm + ar) * K + kt + ac4];
        float4 bv = *(const float4*)&W[(size_t)(kt + bk) * N + bn + bn4];
        __syncthreads();   // previous tile's compute done before overwrite
        As[ac4 + 0][ar] = av.x;
        As[ac4 + 1][ar] = av.y;
        As[ac4 + 2][ar] = av.z;
        As[ac4 + 3][ar] = av.w;
        *(float4*)&Bs[bk][bn4] = bv;
        __syncthreads();
#pragma unroll
        for (int k = 0; k < 8; ++k) {
            float a[8], b[8];
            *(float4*)&a[0] = *(const float4*)&As[k][tm * 8];
            *(float4*)&a[4] = *(const float4*)&As[k][tm * 8 + 4];
            *(float4*)&b[0] = *(const float4*)&Bs[k][tn * 8];
            *(float4*)&b[4] = *(const float4*)&Bs[k][tn * 8 + 4];
#pragma unroll
            for (int i = 0; i < 8; ++i)
#pragma unroll
                for (int j = 0; j < 8; ++j) acc[i][j] += a[i] * b[j];
        }
    }

#pragma unroll
    for (int i = 0; i < 8; ++i) {
        const size_t row = (size_t)(bm + tm * 8 + i);
        float* cp = &Cmat[row * N + bn + tn * 8];
        *(float4*)&cp[0] = make_float4(acc[i][0], acc[i][1], acc[i][2], acc[i][3]);
        *(float4*)&cp[4] = make_float4(acc[i][4], acc[i][5], acc[i][6], acc[i][7]);
    }
}

// ---------------------------------------------------------------------------
// RMSNorm over rows of 128 (per-head). One wave per row, 4 rows per block.
// ---------------------------------------------------------------------------
__global__ __launch_bounds__(256)
void rms128(const float* __restrict__ in, float* __restrict__ out, int nrows) {
    const int row  = blockIdx.x * 4 + (threadIdx.x >> 6);
    const int lane = threadIdx.x & 63;
    if (row >= nrows) return;
    const float* p = in + (size_t)row * DH;
    float2 v = *(const float2*)&p[lane * 2];
    float ss = v.x * v.x + v.y * v.y;
#pragma unroll
    for (int o = 32; o >= 1; o >>= 1) ss += __shfl_xor(ss, o);
    const float sc = rsqrtf(ss * (1.f / DH) + EPSC);
    float* q = out + (size_t)row * DH;
    *(float2*)&q[lane * 2] = make_float2(v.x * sc, v.y * sc);
}

// ---------------------------------------------------------------------------
// RMSNorm over rows of 2048, in place. One block (256 thr) per row.
// ---------------------------------------------------------------------------
__global__ __launch_bounds__(256)
void rms2048_inplace(float* __restrict__ d) {
    __shared__ float red[4];
    const int tid = threadIdx.x;
    float* p = d + (size_t)blockIdx.x * CC;
    float4 a = *(float4*)&p[tid * 8];
    float4 b = *(float4*)&p[tid * 8 + 4];
    float ss = a.x * a.x + a.y * a.y + a.z * a.z + a.w * a.w +
               b.x * b.x + b.y * b.y + b.z * b.z + b.w * b.w;
#pragma unroll
    for (int o = 32; o >= 1; o >>= 1) ss += __shfl_xor(ss, o);
    if ((tid & 63) == 0) red[tid >> 6] = ss;
    __syncthreads();
    const float tot = red[0] + red[1] + red[2] + red[3];
    const float sc = rsqrtf(tot * (1.f / CC) + EPSC);
    a.x *= sc; a.y *= sc; a.z *= sc; a.w *= sc;
    b.x *= sc; b.y *= sc; b.z *= sc; b.w *= sc;
    *(float4*)&p[tid * 8]     = a;
    *(float4*)&p[tid * 8 + 4] = b;
}

// ---------------------------------------------------------------------------
// Flash-style fp32 attention (no mask, no scale — per reference quirks).
// Grid: (T/64 q-tiles, B*HQ). Block 256 threads.
// Q tile 64x128 in LDS; loop over 32-row K/V tiles; online softmax.
// Thread (tq=tid/16, tn=tid%16): owns S[4 q][2 s] and y[4 q][8 d].
// LDS padded to 132 floats/row to break the stride-128 bank conflict (G4).
// ---------------------------------------------------------------------------
__global__ __launch_bounds__(256)
void attn_f32(const float* __restrict__ Qn, const float* __restrict__ Kn,
              const float* __restrict__ V, float* __restrict__ Y) {
    __shared__ float Qs[64][132];
    __shared__ float Ks[32][132];
    __shared__ float Vs[32][132];
    __shared__ float Ps[64][33];

    const int tid = threadIdx.x;
    const int bh  = blockIdx.y;
    const int b   = bh >> 4;
    const int h   = bh & 15;
    const int hk  = h >> 2;
    const int q0  = blockIdx.x * 64;

    const float* qbase = Qn + (size_t)(b * TT) * CC + h * DH;     // stride CC
    const float* kbase = Kn + (size_t)(b * TT) * KVC + hk * DH;   // stride KVC
    const float* vbase = V  + (size_t)(b * TT) * KVC + hk * DH;   // stride KVC

    // load Q tile: 64 rows x 128 (2048 float4, 8 per thread)
    for (int i = tid; i < 64 * 32; i += 256) {
        const int r = i >> 5, c4 = (i & 31) << 2;
        *(float4*)&Qs[r][c4] = *(const float4*)&qbase[(size_t)(q0 + r) * CC + c4];
    }

    const int tq = tid >> 4;   // 0..15 -> q rows tq*4 .. tq*4+3
    const int tn = tid & 15;   // 0..15 -> s cols tn*2, tn*2+1 ; d cols tn*8..+8

    float m[4], l[4], y[4][8];
#pragma unroll
    for (int i = 0; i < 4; ++i) {
        m[i] = -1e30f; l[i] = 0.f;
#pragma unroll
        for (int j = 0; j < 8; ++j) y[i][j] = 0.f;
    }

    for (int st = 0; st < TT; st += 32) {
        __syncthreads();   // previous tile's PV / S reads done
        // stage K,V tiles: 32x128 each (1024 float4 each, 4 per thread)
        for (int i = tid; i < 32 * 32; i += 256) {
            const int r = i >> 5, c4 = (i & 31) << 2;
            *(float4*)&Ks[r][c4] = *(const float4*)&kbase[(size_t)(st + r) * KVC + c4];
            *(float4*)&Vs[r][c4] = *(const float4*)&vbase[(size_t)(st + r) * KVC + c4];
        }
        __syncthreads();

        // S[4][2] = Q[tq*4..][:] . K[tn*2..][:]
        float s[4][2] = {{0.f, 0.f}, {0.f, 0.f}, {0.f, 0.f}, {0.f, 0.f}};
#pragma unroll 4
        for (int k4 = 0; k4 < DH; k4 += 4) {
            const float4 kv0 = *(const float4*)&Ks[tn * 2][k4];
            const float4 kv1 = *(const float4*)&Ks[tn * 2 + 1][k4];
#pragma unroll
            for (int qi = 0; qi < 4; ++qi) {
                const float4 qv = *(const float4*)&Qs[tq * 4 + qi][k4];
                s[qi][0] += qv.x * kv0.x + qv.y * kv0.y + qv.z * kv0.z + qv.w * kv0.w;
                s[qi][1] += qv.x * kv1.x + qv.y * kv1.y + qv.z * kv1.z + qv.w * kv1.w;
            }
        }

        // online softmax update (16-lane butterfly within tq group)
#pragma unroll
        for (int qi = 0; qi < 4; ++qi) {
            float tmax = fmaxf(s[qi][0], s[qi][1]);
#pragma unroll
            for (int o = 8; o >= 1; o >>= 1) tmax = fmaxf(tmax, __shfl_xor(tmax, o));
            const float mn    = fmaxf(m[qi], tmax);
            const float scale = __expf(m[qi] - mn);
            const float p0 = __expf(s[qi][0] - mn);
            const float p1 = __expf(s[qi][1] - mn);
            float ls = p0 + p1;
#pragma unroll
            for (int o = 8; o >= 1; o >>= 1) ls += __shfl_xor(ls, o);
            m[qi] = mn;
            l[qi] = l[qi] * scale + ls;
#pragma unroll
            for (int j = 0; j < 8; ++j) y[qi][j] *= scale;
            Ps[tq * 4 + qi][tn * 2]     = p0;
            Ps[tq * 4 + qi][tn * 2 + 1] = p1;
        }
        __syncthreads();

        // PV: y[qi][0..7] += sum_s Ps[q][s] * V[s][tn*8..]
#pragma unroll 4
        for (int ss = 0; ss < 32; ++ss) {
            const float4 v0 = *(const float4*)&Vs[ss][tn * 8];
            const float4 v1 = *(const float4*)&Vs[ss][tn * 8 + 4];
#pragma unroll
            for (int qi = 0; qi < 4; ++qi) {
                const float p = Ps[tq * 4 + qi][ss];
                y[qi][0] += p * v0.x; y[qi][1] += p * v0.y;
                y[qi][2] += p * v0.z; y[qi][3] += p * v0.w;
                y[qi][4] += p * v1.x; y[qi][5] += p * v1.y;
                y[qi][6] += p * v1.z; y[qi][7] += p * v1.w;
            }
        }
    }

    // finalize: y / l, write to Y[b, t, h*128 + d]
#pragma unroll
    for (int qi = 0; qi < 4; ++qi) {
        const float inv = 1.f / l[qi];
        const int t = q0 + tq * 4 + qi;
        float* yp = Y + (size_t)(b * TT + t) * CC + h * DH + tn * 8;
        *(float4*)&yp[0] = make_float4(y[qi][0] * inv, y[qi][1] * inv,
                                       y[qi][2] * inv, y[qi][3] * inv);
        *(float4*)&yp[4] = make_float4(y[qi][4] * inv, y[qi][5] * inv,
                                       y[qi][6] * inv, y[qi][7] * inv);
    }
}

// ---------------------------------------------------------------------------
extern "C" void kernel_launch(void* const* d_in, const int* in_sizes, int n_in,
                              void* d_out, int out_size, void* d_ws, size_t ws_size,
                              hipStream_t stream) {
    const float* x  = (const float*)d_in[0];
    const float* Wq = (const float*)d_in[1];
    // d_in[2] = Wk — unused by the reference (K = rmsnorm(V))
    const float* Wv = (const float*)d_in[3];
    const float* Wo = (const float*)d_in[4];
    float* out = (float*)d_out;

    // workspace layout (fp32): Q[4096,2048] | V[4096,512] | Kn[4096,512] | Y[4096,2048]
    float* Qb = (float*)d_ws;
    float* Vb = Qb + (size_t)MM * CC;
    float* Kb = Vb + (size_t)MM * KVC;
    float* Yb = Kb + (size_t)MM * KVC;

    const dim3 blk(256);

    // 1) Q = x @ Wq   [4096 x 2048]
    gemm_f32<<<dim3(CC / 128, MM / 128), blk, 0, stream>>>(x, Wq, Qb, MM, CC, CC);
    // 2) V = x @ Wv   [4096 x 512]
    gemm_f32<<<dim3(KVC / 128, MM / 128), blk, 0, stream>>>(x, Wv, Vb, MM, KVC, CC);
    // 3) Q <- rmsnorm per head-row of 128 (in place)
    rms128<<<(MM * HQ_) / 4, blk, 0, stream>>>(Qb, Qb, MM * HQ_);
    // 4) Kn <- rmsnorm(V) per head-row of 128
    rms128<<<(MM * HKV_) / 4, blk, 0, stream>>>(Vb, Kb, MM * HKV_);
    // 5) attention: Y[b,t,h*128+d]
    attn_f32<<<dim3(TT / 64, BB * HQ_), blk, 0, stream>>>(Qb, Kb, Vb, Yb);
    // 6) out_pre = Y @ Wo  -> d_out
    gemm_f32<<<dim3(CC / 128, MM / 128), blk, 0, stream>>>(Yb, Wo, out, MM, CC, CC);
    // 7) out <- rmsnorm rows of 2048 (in place)
    rms2048_inplace<<<MM, blk, 0, stream>>>(out);
}

// Round 4
// 430.959 us; speedup vs baseline: 5.7968x; 5.7968x over previous
//
#include <hip/hip_runtime.h>
#include <math.h>

// Problem constants (B=2, T=2048, C=2048, HQ=16, HKV=4, Dh=128, WIN=256)
#define BB   2
#define TT   2048
#define CC   2048
#define HQ_  16
#define HKV_ 4
#define DH   128
#define MM   (BB * TT)          // 4096 rows
#define KVC  (HKV_ * DH)        // 512

typedef __attribute__((ext_vector_type(8))) _Float16 f16x8;
typedef __attribute__((ext_vector_type(4))) float    f32x4;

__device__ __forceinline__ unsigned short f2h(float x) {
    _Float16 h = (_Float16)x;                 // RNE v_cvt_f16_f32
    return __builtin_bit_cast(unsigned short, h);
}
__device__ __forceinline__ float h2f(unsigned short u) {
    return (float)__builtin_bit_cast(_Float16, u);
}
__device__ __forceinline__ void gll16(const void* g, void* l) {
    __builtin_amdgcn_global_load_lds(
        (const __attribute__((address_space(1))) unsigned int*)g,
        (__attribute__((address_space(3))) unsigned int*)l, 16, 0, 0);
}

// ---------------------------------------------------------------------------
// fp32 -> fp16 cast, 8 elems/thread
// ---------------------------------------------------------------------------
__global__ __launch_bounds__(256)
void cast_f16(const float* __restrict__ in, unsigned short* __restrict__ out, int n8) {
    int i = blockIdx.x * blockDim.x + threadIdx.x;
    const int stride = gridDim.x * blockDim.x;
    for (; i < n8; i += stride) {
        const float4 a = ((const float4*)in)[i * 2 + 0];
        const float4 b = ((const float4*)in)[i * 2 + 1];
        uint4 o;
        o.x = (unsigned)f2h(a.x) | ((unsigned)f2h(a.y) << 16);
        o.y = (unsigned)f2h(a.z) | ((unsigned)f2h(a.w) << 16);
        o.z = (unsigned)f2h(b.x) | ((unsigned)f2h(b.y) << 16);
        o.w = (unsigned)f2h(b.z) | ((unsigned)f2h(b.w) << 16);
        ((uint4*)out)[i] = o;
    }
}

// ---------------------------------------------------------------------------
// Transpose-cast: W[Kd][Nd] fp32 -> WT[Nd][Kd] fp16. 32x32 tiles.
// ---------------------------------------------------------------------------
__global__ __launch_bounds__(256)
void tcast(const float* __restrict__ W, unsigned short* __restrict__ WT, int Kd, int Nd) {
    __shared__ float Ls[32][33];
    const int n0 = blockIdx.x * 32, k0 = blockIdx.y * 32;
    const int i = threadIdx.x;
    {
        const int kr = i >> 3, n4 = (i & 7) * 4;
        float4 v = *(const float4*)&W[(size_t)(k0 + kr) * Nd + n0 + n4];
        Ls[kr][n4 + 0] = v.x; Ls[kr][n4 + 1] = v.y;
        Ls[kr][n4 + 2] = v.z; Ls[kr][n4 + 3] = v.w;
    }
    __syncthreads();
    {
        const int nr = i >> 3, k4 = (i & 7) * 4;
        uint2 o;
        o.x = (unsigned)f2h(Ls[k4 + 0][nr]) | ((unsigned)f2h(Ls[k4 + 1][nr]) << 16);
        o.y = (unsigned)f2h(Ls[k4 + 2][nr]) | ((unsigned)f2h(Ls[k4 + 3][nr]) << 16);
        *(uint2*)&WT[(size_t)(n0 + nr) * Kd + k0 + k4] = o;
    }
}

// ---------------------------------------------------------------------------
// fp16 MFMA GEMM, B^T input: C[M][N] = A[M][K] * Bt[N][K]^T
// 128x128 tile, BK=64, 4 waves, acc 4x4 frags/wave, global_load_lds staging,
// 3-bit XOR chunk-swizzle (pre-swizzled global source, swizzled ds_read).
// ---------------------------------------------------------------------------
template<int F16OUT>
__global__ __launch_bounds__(256)
void gemm_bt(const unsigned short* __restrict__ A, const unsigned short* __restrict__ Bt,
             void* __restrict__ Cout, int M, int N, int K) {
    __shared__ __align__(16) unsigned short As[128 * 64];
    __shared__ __align__(16) unsigned short Bs[128 * 64];
    const int tid  = threadIdx.x;
    const int lane = tid & 63, wid = tid >> 6;
    const int g = lane >> 4, l15 = lane & 15;
    const int bm = blockIdx.y * 128, bn = blockIdx.x * 128;
    const int wr = (wid >> 1) * 64, wc = (wid & 1) * 64;

    f32x4 acc[4][4] = {};

    for (int kt = 0; kt < K; kt += 64) {
        __syncthreads();
#pragma unroll
        for (int r = 0; r < 4; ++r) {
            const int q = r * 256 + tid;
            const int row = q >> 3, c = q & 7, sc = c ^ (row & 7);
            gll16(A + (size_t)(bm + row) * K + kt + sc * 8, As + q * 8);
        }
#pragma unroll
        for (int r = 0; r < 4; ++r) {
            const int q = r * 256 + tid;
            const int row = q >> 3, c = q & 7, sc = c ^ (row & 7);
            gll16(Bt + (size_t)(bn + row) * K + kt + sc * 8, Bs + q * 8);
        }
        __syncthreads();

#pragma unroll
        for (int kk = 0; kk < 2; ++kk) {
            f16x8 af[4], bfr[4];
#pragma unroll
            for (int m = 0; m < 4; ++m) {
                const int row = wr + m * 16 + l15;
                const int ch = (kk * 4 + g) ^ (row & 7);
                af[m] = *(const f16x8*)&As[row * 64 + ch * 8];
            }
#pragma unroll
            for (int n = 0; n < 4; ++n) {
                const int row = wc + n * 16 + l15;
                const int ch = (kk * 4 + g) ^ (row & 7);
                bfr[n] = *(const f16x8*)&Bs[row * 64 + ch * 8];
            }
#pragma unroll
            for (int m = 0; m < 4; ++m)
#pragma unroll
                for (int n = 0; n < 4; ++n)
                    acc[m][n] = __builtin_amdgcn_mfma_f32_16x16x32_f16(
                        af[m], bfr[n], acc[m][n], 0, 0, 0);
        }
    }

#pragma unroll
    for (int m = 0; m < 4; ++m)
#pragma unroll
        for (int n = 0; n < 4; ++n)
#pragma unroll
            for (int r = 0; r < 4; ++r) {
                const int row = bm + wr + m * 16 + g * 4 + r;
                const int col = bn + wc + n * 16 + l15;
                const float v = acc[m][n][r];
                if (F16OUT)
                    ((unsigned short*)Cout)[(size_t)row * N + col] = f2h(v);
                else
                    ((float*)Cout)[(size_t)row * N + col] = v;
            }
}

// ---------------------------------------------------------------------------
// RMSNorm over rows of 128, fp16 in -> fp16 out (in-place safe). Wave/row.
// ---------------------------------------------------------------------------
__global__ __launch_bounds__(256)
void rms128_h(const unsigned short* __restrict__ in, unsigned short* __restrict__ out,
              int nrows) {
    const int row  = blockIdx.x * 4 + (threadIdx.x >> 6);
    const int lane = threadIdx.x & 63;
    if (row >= nrows) return;
    const unsigned u = *(const unsigned*)(in + (size_t)row * DH + lane * 2);
    const float a = h2f((unsigned short)(u & 0xffff));
    const float b = h2f((unsigned short)(u >> 16));
    float ss = a * a + b * b;
#pragma unroll
    for (int o = 32; o >= 1; o >>= 1) ss += __shfl_xor(ss, o);
    const float sc = rsqrtf(ss * (1.f / DH) + 1.1920929e-07f);
    const unsigned ov = (unsigned)f2h(a * sc) | ((unsigned)f2h(b * sc) << 16);
    *(unsigned*)(out + (size_t)row * DH + lane * 2) = ov;
}

// ---------------------------------------------------------------------------
// Build Vt[b][hk][d][t] fp16 from Vg[b*T][512] fp16 (32x32 transpose tiles)
// ---------------------------------------------------------------------------
__global__ __launch_bounds__(256)
void vt_build(const unsigned short* __restrict__ Vg, unsigned short* __restrict__ Vt) {
    __shared__ unsigned short Ls[32][36];
    const int t0 = blockIdx.x * 32;
    const int d0 = blockIdx.y * 32;
    const int bh = blockIdx.z;            // b*4 + hk
    const int b = bh >> 2, hk = bh & 3;
    const int i = threadIdx.x;
    {
        const int tr = i >> 3, d4 = (i & 7) * 4;
        const unsigned short* src = Vg + (size_t)(b * TT + t0 + tr) * KVC + hk * DH + d0 + d4;
        const unsigned u0 = *(const unsigned*)(src);
        const unsigned u1 = *(const unsigned*)(src + 2);
        Ls[tr][d4 + 0] = (unsigned short)(u0 & 0xffff);
        Ls[tr][d4 + 1] = (unsigned short)(u0 >> 16);
        Ls[tr][d4 + 2] = (unsigned short)(u1 & 0xffff);
        Ls[tr][d4 + 3] = (unsigned short)(u1 >> 16);
    }
    __syncthreads();
    {
        const int dr = i >> 3, t4 = (i & 7) * 4;
        unsigned short* dst = Vt + ((size_t)bh * DH + d0 + dr) * TT + t0 + t4;
        const unsigned o0 = (unsigned)Ls[t4 + 0][dr] | ((unsigned)Ls[t4 + 1][dr] << 16);
        const unsigned o1 = (unsigned)Ls[t4 + 2][dr] | ((unsigned)Ls[t4 + 3][dr] << 16);
        *(unsigned*)(dst)     = o0;
        *(unsigned*)(dst + 2) = o1;
    }
}

// ---------------------------------------------------------------------------
// Flash attention, fp16 MFMA. No mask, no 1/sqrt(d) scale (reference quirks).
// Block: 256 thr (4 waves), 64 q-rows (16/wave). KT=64 key tiles.
// K staged [64][128] swizzled; Vt staged [128][64] swizzled; per-wave P LDS.
// ---------------------------------------------------------------------------
__global__ __launch_bounds__(256)
void attn_mfma(const unsigned short* __restrict__ Qb, const unsigned short* __restrict__ Kb,
               const unsigned short* __restrict__ Vt, unsigned short* __restrict__ Yb) {
    __shared__ __align__(16) unsigned short Ks[64 * 128];
    __shared__ __align__(16) unsigned short Vs[128 * 64];
    __shared__ __align__(16) unsigned short Ps[4][16 * 64];

    const int tid  = threadIdx.x;
    const int lane = tid & 63, wid = tid >> 6;
    const int g = lane >> 4, l15 = lane & 15;
    const int q0 = blockIdx.x * 64;
    const int bh = blockIdx.y;
    const int b = bh >> 4, h = bh & 15, hk = h >> 2;

    // Q fragments in registers (16 q-rows per wave, Dh=128 -> 4 k-chunks)
    f16x8 qf[4];
    {
        const unsigned short* qp =
            Qb + (size_t)(b * TT + q0 + wid * 16 + l15) * CC + h * DH + g * 8;
#pragma unroll
        for (int kk = 0; kk < 4; ++kk) qf[kk] = *(const f16x8*)(qp + kk * 32);
    }

    float mr[4], lr[4];
    f32x4 acc[8] = {};
#pragma unroll
    for (int r = 0; r < 4; ++r) { mr[r] = -3.0e38f; lr[r] = 0.f; }

    const size_t kbase = (size_t)(b * TT) * KVC + hk * DH;
    const size_t vbase = (size_t)(b * HKV_ + hk) * DH * TT;

    for (int st = 0; st < TT; st += 64) {
        __syncthreads();
#pragma unroll
        for (int r = 0; r < 4; ++r) {         // K tile: 64 rows x 16 chunks
            const int q = r * 256 + tid;
            const int key = q >> 4, c = q & 15, sc = c ^ (key & 7);
            gll16(Kb + kbase + (size_t)(st + key) * KVC + sc * 8, Ks + q * 8);
        }
#pragma unroll
        for (int r = 0; r < 4; ++r) {         // Vt tile: 128 rows x 8 chunks
            const int q = r * 256 + tid;
            const int d = q >> 3, c = q & 7, sc = c ^ (d & 7);
            gll16(Vt + vbase + (size_t)d * TT + st + sc * 8, Vs + q * 8);
        }
        __syncthreads();

        // S = Q K^T  (4 col-frags x 4 dh-steps)
        f32x4 s[4] = {};
#pragma unroll
        for (int kk = 0; kk < 4; ++kk)
#pragma unroll
            for (int n = 0; n < 4; ++n) {
                const int key = n * 16 + l15;
                const int ch = (kk * 4 + g) ^ (key & 7);
                const f16x8 kf = *(const f16x8*)&Ks[key * 128 + ch * 8];
                s[n] = __builtin_amdgcn_mfma_f32_16x16x32_f16(qf[kk], kf, s[n], 0, 0, 0);
            }

        // online softmax (wave-parallel, 16-lane-group butterflies)
        float p[4][4], scale[4];
#pragma unroll
        for (int r = 0; r < 4; ++r) {
            float mx = fmaxf(fmaxf(s[0][r], s[1][r]), fmaxf(s[2][r], s[3][r]));
#pragma unroll
            for (int o = 8; o >= 1; o >>= 1) mx = fmaxf(mx, __shfl_xor(mx, o));
            const float mn = fmaxf(mr[r], mx);
            scale[r] = __expf(mr[r] - mn);
            mr[r] = mn;
            float ls = 0.f;
#pragma unroll
            for (int n = 0; n < 4; ++n) { p[n][r] = __expf(s[n][r] - mn); ls += p[n][r]; }
#pragma unroll
            for (int o = 8; o >= 1; o >>= 1) ls += __shfl_xor(ls, o);
            lr[r] = lr[r] * scale[r] + ls;
        }
#pragma unroll
        for (int f = 0; f < 8; ++f) {
            acc[f][0] *= scale[0]; acc[f][1] *= scale[1];
            acc[f][2] *= scale[2]; acc[f][3] *= scale[3];
        }

        // P -> per-wave LDS (swizzled), fp16
        unsigned short* pw = Ps[wid];
#pragma unroll
        for (int n = 0; n < 4; ++n) {
            const int colc = n * 2 + (l15 >> 3);
            const int cel  = l15 & 7;
#pragma unroll
            for (int r = 0; r < 4; ++r) {
                const int row = g * 4 + r;
                const int ch = colc ^ (row & 7);
                pw[row * 64 + ch * 8 + cel] = f2h(p[n][r]);
            }
        }

        // Y += P V  (A = P[16x64] -> 2 k-steps; B = Vt slices)
#pragma unroll
        for (int ks = 0; ks < 2; ++ks) {
            const int ch = (ks * 4 + g) ^ (l15 & 7);
            const f16x8 pa = *(const f16x8*)&pw[l15 * 64 + ch * 8];
#pragma unroll
            for (int f = 0; f < 8; ++f) {
                const int dr = f * 16 + l15;
                const int vch = (ks * 4 + g) ^ (dr & 7);
                const f16x8 vf = *(const f16x8*)&Vs[dr * 64 + vch * 8];
                acc[f] = __builtin_amdgcn_mfma_f32_16x16x32_f16(pa, vf, acc[f], 0, 0, 0);
            }
        }
    }

    // finalize and store fp16 Y
    float inv[4];
#pragma unroll
    for (int r = 0; r < 4; ++r) inv[r] = 1.f / lr[r];
#pragma unroll
    for (int f = 0; f < 8; ++f)
#pragma unroll
        for (int r = 0; r < 4; ++r) {
            const int t = q0 + wid * 16 + g * 4 + r;
            const int col = h * DH + f * 16 + l15;
            Yb[(size_t)(b * TT + t) * CC + col] = f2h(acc[f][r] * inv[r]);
        }
}

// ---------------------------------------------------------------------------
// RMSNorm rows of 2048, fp32 in-place (final output norm)
// ---------------------------------------------------------------------------
__global__ __launch_bounds__(256)
void rms2048_inplace(float* __restrict__ d) {
    __shared__ float red[4];
    const int tid = threadIdx.x;
    float* p = d + (size_t)blockIdx.x * CC;
    float4 a = *(float4*)&p[tid * 8];
    float4 b = *(float4*)&p[tid * 8 + 4];
    float ss = a.x * a.x + a.y * a.y + a.z * a.z + a.w * a.w +
               b.x * b.x + b.y * b.y + b.z * b.z + b.w * b.w;
#pragma unroll
    for (int o = 32; o >= 1; o >>= 1) ss += __shfl_xor(ss, o);
    if ((tid & 63) == 0) red[tid >> 6] = ss;
    __syncthreads();
    const float tot = red[0] + red[1] + red[2] + red[3];
    const float sc = rsqrtf(tot * (1.f / CC) + 1.1920929e-07f);
    a.x *= sc; a.y *= sc; a.z *= sc; a.w *= sc;
    b.x *= sc; b.y *= sc; b.z *= sc; b.w *= sc;
    *(float4*)&p[tid * 8]     = a;
    *(float4*)&p[tid * 8 + 4] = b;
}

// ---------------------------------------------------------------------------
extern "C" void kernel_launch(void* const* d_in, const int* in_sizes, int n_in,
                              void* d_out, int out_size, void* d_ws, size_t ws_size,
                              hipStream_t stream) {
    const float* x  = (const float*)d_in[0];
    const float* Wq = (const float*)d_in[1];
    // d_in[2] = Wk — unused by the reference (K = rmsnorm(V))
    const float* Wv = (const float*)d_in[3];
    const float* Wo = (const float*)d_in[4];
    float* out = (float*)d_out;

    char* ws = (char*)d_ws;
    const size_t MB = 1024 * 1024;
    unsigned short* xb  = (unsigned short*)(ws);             // 16 MB
    unsigned short* WqT = (unsigned short*)(ws + 16 * MB);   //  8 MB
    unsigned short* WoT = WqT;                               // reuse after gemm Q
    unsigned short* WvT = (unsigned short*)(ws + 24 * MB);   //  2 MB
    unsigned short* Qg  = (unsigned short*)(ws + 26 * MB);   // 16 MB
    unsigned short* Vg  = (unsigned short*)(ws + 42 * MB);   //  4 MB
    unsigned short* Kb  = (unsigned short*)(ws + 46 * MB);   //  4 MB
    unsigned short* Vt  = (unsigned short*)(ws + 50 * MB);   //  4 MB
    unsigned short* Yb  = (unsigned short*)(ws + 54 * MB);   // 16 MB  (peak 70 MB)

    const dim3 blk(256);

    cast_f16<<<2048, blk, 0, stream>>>(x, xb, MM * CC / 8);
    tcast<<<dim3(CC / 32, CC / 32), blk, 0, stream>>>(Wq, WqT, CC, CC);
    tcast<<<dim3(KVC / 32, CC / 32), blk, 0, stream>>>(Wv, WvT, CC, KVC);

    gemm_bt<1><<<dim3(CC / 128, MM / 128), blk, 0, stream>>>(xb, WqT, Qg, MM, CC, CC);
    gemm_bt<1><<<dim3(KVC / 128, MM / 128), blk, 0, stream>>>(xb, WvT, Vg, MM, KVC, CC);

    tcast<<<dim3(CC / 32, CC / 32), blk, 0, stream>>>(Wo, WoT, CC, CC);  // after gemm Q

    rms128_h<<<MM * HQ_ / 4, blk, 0, stream>>>(Qg, Qg, MM * HQ_);        // Q norm, in place
    rms128_h<<<MM * HKV_ / 4, blk, 0, stream>>>(Vg, Kb, MM * HKV_);      // K = norm(V)
    vt_build<<<dim3(TT / 32, DH / 32, BB * HKV_), blk, 0, stream>>>(Vg, Vt);

    attn_mfma<<<dim3(TT / 64, BB * HQ_), blk, 0, stream>>>(Qg, Kb, Vt, Yb);

    gemm_bt<0><<<dim3(CC / 128, MM / 128), blk, 0, stream>>>(Yb, WoT, out, MM, CC, CC);
    rms2048_inplace<<<MM, blk, 0, stream>>>(out);
}

// Round 5
// 327.328 us; speedup vs baseline: 7.6320x; 1.3166x over previous
//
#include <hip/hip_runtime.h>
#include <math.h>

// Problem constants (B=2, T=2048, C=2048, HQ=16, HKV=4, Dh=128, WIN=256)
#define BB   2
#define TT   2048
#define CC   2048
#define HQ_  16
#define HKV_ 4
#define DH   128
#define MM   (BB * TT)          // 4096 rows
#define KVC  (HKV_ * DH)        // 512

typedef __attribute__((ext_vector_type(8))) _Float16 f16x8;
typedef __attribute__((ext_vector_type(4))) float    f32x4;

__device__ __forceinline__ unsigned short f2h(float x) {
    _Float16 h = (_Float16)x;                 // RNE v_cvt_f16_f32
    return __builtin_bit_cast(unsigned short, h);
}
__device__ __forceinline__ float h2f(unsigned short u) {
    return (float)__builtin_bit_cast(_Float16, u);
}
__device__ __forceinline__ void gll16(const void* g, void* l) {
    __builtin_amdgcn_global_load_lds(
        (const __attribute__((address_space(1))) unsigned int*)g,
        (__attribute__((address_space(3))) unsigned int*)l, 16, 0, 0);
}

// ---------------------------------------------------------------------------
// fp32 -> fp16 cast, 8 elems/thread
// ---------------------------------------------------------------------------
__global__ __launch_bounds__(256)
void cast_f16(const float* __restrict__ in, unsigned short* __restrict__ out, int n8) {
    int i = blockIdx.x * blockDim.x + threadIdx.x;
    const int stride = gridDim.x * blockDim.x;
    for (; i < n8; i += stride) {
        const float4 a = ((const float4*)in)[i * 2 + 0];
        const float4 b = ((const float4*)in)[i * 2 + 1];
        uint4 o;
        o.x = (unsigned)f2h(a.x) | ((unsigned)f2h(a.y) << 16);
        o.y = (unsigned)f2h(a.z) | ((unsigned)f2h(a.w) << 16);
        o.z = (unsigned)f2h(b.x) | ((unsigned)f2h(b.y) << 16);
        o.w = (unsigned)f2h(b.z) | ((unsigned)f2h(b.w) << 16);
        ((uint4*)out)[i] = o;
    }
}

// ---------------------------------------------------------------------------
// Transpose-cast: W[Kd][Nd] fp32 -> WT[Nd][Kd] fp16. 32x32 tiles.
// ---------------------------------------------------------------------------
__global__ __launch_bounds__(256)
void tcast(const float* __restrict__ W, unsigned short* __restrict__ WT, int Kd, int Nd) {
    __shared__ float Ls[32][33];
    const int n0 = blockIdx.x * 32, k0 = blockIdx.y * 32;
    const int i = threadIdx.x;
    {
        const int kr = i >> 3, n4 = (i & 7) * 4;
        float4 v = *(const float4*)&W[(size_t)(k0 + kr) * Nd + n0 + n4];
        Ls[kr][n4 + 0] = v.x; Ls[kr][n4 + 1] = v.y;
        Ls[kr][n4 + 2] = v.z; Ls[kr][n4 + 3] = v.w;
    }
    __syncthreads();
    {
        const int nr = i >> 3, k4 = (i & 7) * 4;
        uint2 o;
        o.x = (unsigned)f2h(Ls[k4 + 0][nr]) | ((unsigned)f2h(Ls[k4 + 1][nr]) << 16);
        o.y = (unsigned)f2h(Ls[k4 + 2][nr]) | ((unsigned)f2h(Ls[k4 + 3][nr]) << 16);
        *(uint2*)&WT[(size_t)(n0 + nr) * Kd + k0 + k4] = o;
    }
}

// ---------------------------------------------------------------------------
// fp16 MFMA GEMM, B^T input: C[M][N] = A[M][K] * Bt[N][K]^T
// 128x128 tile, BK=64, 4 waves, acc 4x4 frags/wave, global_load_lds staging,
// 3-bit XOR chunk-swizzle (pre-swizzled global source, swizzled ds_read).
// ---------------------------------------------------------------------------
template<int F16OUT>
__global__ __launch_bounds__(256)
void gemm_bt(const unsigned short* __restrict__ A, const unsigned short* __restrict__ Bt,
             void* __restrict__ Cout, int M, int N, int K) {
    __shared__ __align__(16) unsigned short As[128 * 64];
    __shared__ __align__(16) unsigned short Bs[128 * 64];
    const int tid  = threadIdx.x;
    const int lane = tid & 63, wid = tid >> 6;
    const int g = lane >> 4, l15 = lane & 15;
    const int bm = blockIdx.y * 128, bn = blockIdx.x * 128;
    const int wr = (wid >> 1) * 64, wc = (wid & 1) * 64;

    f32x4 acc[4][4] = {};

    for (int kt = 0; kt < K; kt += 64) {
        __syncthreads();
#pragma unroll
        for (int r = 0; r < 4; ++r) {
            const int q = r * 256 + tid;
            const int row = q >> 3, c = q & 7, sc = c ^ (row & 7);
            gll16(A + (size_t)(bm + row) * K + kt + sc * 8, As + q * 8);
        }
#pragma unroll
        for (int r = 0; r < 4; ++r) {
            const int q = r * 256 + tid;
            const int row = q >> 3, c = q & 7, sc = c ^ (row & 7);
            gll16(Bt + (size_t)(bn + row) * K + kt + sc * 8, Bs + q * 8);
        }
        __syncthreads();

#pragma unroll
        for (int kk = 0; kk < 2; ++kk) {
            f16x8 af[4], bfr[4];
#pragma unroll
            for (int m = 0; m < 4; ++m) {
                const int row = wr + m * 16 + l15;
                const int ch = (kk * 4 + g) ^ (row & 7);
                af[m] = *(const f16x8*)&As[row * 64 + ch * 8];
            }
#pragma unroll
            for (int n = 0; n < 4; ++n) {
                const int row = wc + n * 16 + l15;
                const int ch = (kk * 4 + g) ^ (row & 7);
                bfr[n] = *(const f16x8*)&Bs[row * 64 + ch * 8];
            }
#pragma unroll
            for (int m = 0; m < 4; ++m)
#pragma unroll
                for (int n = 0; n < 4; ++n)
                    acc[m][n] = __builtin_amdgcn_mfma_f32_16x16x32_f16(
                        af[m], bfr[n], acc[m][n], 0, 0, 0);
        }
    }

#pragma unroll
    for (int m = 0; m < 4; ++m)
#pragma unroll
        for (int n = 0; n < 4; ++n)
#pragma unroll
            for (int r = 0; r < 4; ++r) {
                const int row = bm + wr + m * 16 + g * 4 + r;
                const int col = bn + wc + n * 16 + l15;
                const float v = acc[m][n][r];
                if (F16OUT)
                    ((unsigned short*)Cout)[(size_t)row * N + col] = f2h(v);
                else
                    ((float*)Cout)[(size_t)row * N + col] = v;
            }
}

// ---------------------------------------------------------------------------
// RMSNorm over rows of 128, fp16 in -> fp16 out (in-place safe). Wave/row.
// ---------------------------------------------------------------------------
__global__ __launch_bounds__(256)
void rms128_h(const unsigned short* __restrict__ in, unsigned short* __restrict__ out,
              int nrows) {
    const int row  = blockIdx.x * 4 + (threadIdx.x >> 6);
    const int lane = threadIdx.x & 63;
    if (row >= nrows) return;
    const unsigned u = *(const unsigned*)(in + (size_t)row * DH + lane * 2);
    const float a = h2f((unsigned short)(u & 0xffff));
    const float b = h2f((unsigned short)(u >> 16));
    float ss = a * a + b * b;
#pragma unroll
    for (int o = 32; o >= 1; o >>= 1) ss += __shfl_xor(ss, o);
    const float sc = rsqrtf(ss * (1.f / DH) + 1.1920929e-07f);
    const unsigned ov = (unsigned)f2h(a * sc) | ((unsigned)f2h(b * sc) << 16);
    *(unsigned*)(out + (size_t)row * DH + lane * 2) = ov;
}

// ---------------------------------------------------------------------------
// Build Vt[b][hk][d][t] fp16 from Vg[b*T][512] fp16 (32x32 transpose tiles)
// ---------------------------------------------------------------------------
__global__ __launch_bounds__(256)
void vt_build(const unsigned short* __restrict__ Vg, unsigned short* __restrict__ Vt) {
    __shared__ unsigned short Ls[32][36];
    const int t0 = blockIdx.x * 32;
    const int d0 = blockIdx.y * 32;
    const int bh = blockIdx.z;            // b*4 + hk
    const int b = bh >> 2, hk = bh & 3;
    const int i = threadIdx.x;
    {
        const int tr = i >> 3, d4 = (i & 7) * 4;
        const unsigned short* src = Vg + (size_t)(b * TT + t0 + tr) * KVC + hk * DH + d0 + d4;
        const unsigned u0 = *(const unsigned*)(src);
        const unsigned u1 = *(const unsigned*)(src + 2);
        Ls[tr][d4 + 0] = (unsigned short)(u0 & 0xffff);
        Ls[tr][d4 + 1] = (unsigned short)(u0 >> 16);
        Ls[tr][d4 + 2] = (unsigned short)(u1 & 0xffff);
        Ls[tr][d4 + 3] = (unsigned short)(u1 >> 16);
    }
    __syncthreads();
    {
        const int dr = i >> 3, t4 = (i & 7) * 4;
        unsigned short* dst = Vt + ((size_t)bh * DH + d0 + dr) * TT + t0 + t4;
        const unsigned o0 = (unsigned)Ls[t4 + 0][dr] | ((unsigned)Ls[t4 + 1][dr] << 16);
        const unsigned o1 = (unsigned)Ls[t4 + 2][dr] | ((unsigned)Ls[t4 + 3][dr] << 16);
        *(unsigned*)(dst)     = o0;
        *(unsigned*)(dst + 2) = o1;
    }
}

// ---------------------------------------------------------------------------
// Flash attention, fp16 MFMA. No mask, no 1/sqrt(d) scale (reference quirks).
// Block: 256 thr (4 waves), 64 q-rows (16/wave). KT=64 key tiles.
// R5: __launch_bounds__(256,4) (VGPR<=128, 4 blocks/CU), T5 setprio around
// MFMA clusters, T13 defer-max (THR=8, P bounded by e^8 -- fp16-safe).
// ---------------------------------------------------------------------------
__global__ __launch_bounds__(256, 4)
void attn_mfma(const unsigned short* __restrict__ Qb, const unsigned short* __restrict__ Kb,
               const unsigned short* __restrict__ Vt, unsigned short* __restrict__ Yb) {
    __shared__ __align__(16) unsigned short Ks[64 * 128];
    __shared__ __align__(16) unsigned short Vs[128 * 64];
    __shared__ __align__(16) unsigned short Ps[4][16 * 64];

    const int tid  = threadIdx.x;
    const int lane = tid & 63, wid = tid >> 6;
    const int g = lane >> 4, l15 = lane & 15;
    const int q0 = blockIdx.x * 64;
    const int bh = blockIdx.y;
    const int b = bh >> 4, h = bh & 15, hk = h >> 2;

    // Q fragments in registers (16 q-rows per wave, Dh=128 -> 4 k-chunks)
    f16x8 qf[4];
    {
        const unsigned short* qp =
            Qb + (size_t)(b * TT + q0 + wid * 16 + l15) * CC + h * DH + g * 8;
#pragma unroll
        for (int kk = 0; kk < 4; ++kk) qf[kk] = *(const f16x8*)(qp + kk * 32);
    }

    float mr[4], lr[4];
    f32x4 acc[8] = {};
#pragma unroll
    for (int r = 0; r < 4; ++r) { mr[r] = -3.0e38f; lr[r] = 0.f; }

    const size_t kbase = (size_t)(b * TT) * KVC + hk * DH;
    const size_t vbase = (size_t)(b * HKV_ + hk) * DH * TT;

    for (int st = 0; st < TT; st += 64) {
        __syncthreads();
#pragma unroll
        for (int r = 0; r < 4; ++r) {         // K tile: 64 rows x 16 chunks
            const int q = r * 256 + tid;
            const int key = q >> 4, c = q & 15, sc = c ^ (key & 7);
            gll16(Kb + kbase + (size_t)(st + key) * KVC + sc * 8, Ks + q * 8);
        }
#pragma unroll
        for (int r = 0; r < 4; ++r) {         // Vt tile: 128 rows x 8 chunks
            const int q = r * 256 + tid;
            const int d = q >> 3, c = q & 7, sc = c ^ (d & 7);
            gll16(Vt + vbase + (size_t)d * TT + st + sc * 8, Vs + q * 8);
        }
        __syncthreads();

        // S = Q K^T  (4 col-frags x 4 dh-steps)
        f32x4 s[4] = {};
        __builtin_amdgcn_s_setprio(1);
#pragma unroll
        for (int kk = 0; kk < 4; ++kk)
#pragma unroll
            for (int n = 0; n < 4; ++n) {
                const int key = n * 16 + l15;
                const int ch = (kk * 4 + g) ^ (key & 7);
                const f16x8 kf = *(const f16x8*)&Ks[key * 128 + ch * 8];
                s[n] = __builtin_amdgcn_mfma_f32_16x16x32_f16(qf[kk], kf, s[n], 0, 0, 0);
            }
        __builtin_amdgcn_s_setprio(0);

        // tile max per row (16-lane-group butterflies)
        float mx[4];
        bool need = false;
#pragma unroll
        for (int r = 0; r < 4; ++r) {
            float m0 = fmaxf(fmaxf(s[0][r], s[1][r]), fmaxf(s[2][r], s[3][r]));
#pragma unroll
            for (int o = 8; o >= 1; o >>= 1) m0 = fmaxf(m0, __shfl_xor(m0, o));
            mx[r] = m0;
            need = need || (m0 > mr[r] + 8.f);
        }
        // T13 defer-max: only rescale when some row's max grew past THR=8
        if (__any(need)) {
            float scale[4];
#pragma unroll
            for (int r = 0; r < 4; ++r) {
                const float mn = fmaxf(mr[r], mx[r]);
                scale[r] = __expf(mr[r] - mn);
                mr[r] = mn;
                lr[r] *= scale[r];
            }
#pragma unroll
            for (int f = 0; f < 8; ++f) {
                acc[f][0] *= scale[0]; acc[f][1] *= scale[1];
                acc[f][2] *= scale[2]; acc[f][3] *= scale[3];
            }
        }

        // P = exp(S - m), row-sum into l
        float p[4][4];
#pragma unroll
        for (int r = 0; r < 4; ++r) {
            float ls = 0.f;
#pragma unroll
            for (int n = 0; n < 4; ++n) { p[n][r] = __expf(s[n][r] - mr[r]); ls += p[n][r]; }
#pragma unroll
            for (int o = 8; o >= 1; o >>= 1) ls += __shfl_xor(ls, o);
            lr[r] += ls;
        }

        // P -> per-wave LDS (swizzled), fp16
        unsigned short* pw = Ps[wid];
#pragma unroll
        for (int n = 0; n < 4; ++n) {
            const int colc = n * 2 + (l15 >> 3);
            const int cel  = l15 & 7;
#pragma unroll
            for (int r = 0; r < 4; ++r) {
                const int row = g * 4 + r;
                const int ch = colc ^ (row & 7);
                pw[row * 64 + ch * 8 + cel] = f2h(p[n][r]);
            }
        }

        // Y += P V  (A = P[16x64] -> 2 k-steps; B = Vt slices)
        __builtin_amdgcn_s_setprio(1);
#pragma unroll
        for (int ks = 0; ks < 2; ++ks) {
            const int ch = (ks * 4 + g) ^ (l15 & 7);
            const f16x8 pa = *(const f16x8*)&pw[l15 * 64 + ch * 8];
#pragma unroll
            for (int f = 0; f < 8; ++f) {
                const int dr = f * 16 + l15;
                const int vch = (ks * 4 + g) ^ (dr & 7);
                const f16x8 vf = *(const f16x8*)&Vs[dr * 64 + vch * 8];
                acc[f] = __builtin_amdgcn_mfma_f32_16x16x32_f16(pa, vf, acc[f], 0, 0, 0);
            }
        }
        __builtin_amdgcn_s_setprio(0);
    }

    // finalize and store fp16 Y
    float inv[4];
#pragma unroll
    for (int r = 0; r < 4; ++r) inv[r] = 1.f / lr[r];
#pragma unroll
    for (int f = 0; f < 8; ++f)
#pragma unroll
        for (int r = 0; r < 4; ++r) {
            const int t = q0 + wid * 16 + g * 4 + r;
            const int col = h * DH + f * 16 + l15;
            Yb[(size_t)(b * TT + t) * CC + col] = f2h(acc[f][r] * inv[r]);
        }
}

// ---------------------------------------------------------------------------
// RMSNorm rows of 2048, fp32 in-place (final output norm)
// ---------------------------------------------------------------------------
__global__ __launch_bounds__(256)
void rms2048_inplace(float* __restrict__ d) {
    __shared__ float red[4];
    const int tid = threadIdx.x;
    float* p = d + (size_t)blockIdx.x * CC;
    float4 a = *(float4*)&p[tid * 8];
    float4 b = *(float4*)&p[tid * 8 + 4];
    float ss = a.x * a.x + a.y * a.y + a.z * a.z + a.w * a.w +
               b.x * b.x + b.y * b.y + b.z * b.z + b.w * b.w;
#pragma unroll
    for (int o = 32; o >= 1; o >>= 1) ss += __shfl_xor(ss, o);
    if ((tid & 63) == 0) red[tid >> 6] = ss;
    __syncthreads();
    const float tot = red[0] + red[1] + red[2] + red[3];
    const float sc = rsqrtf(tot * (1.f / CC) + 1.1920929e-07f);
    a.x *= sc; a.y *= sc; a.z *= sc; a.w *= sc;
    b.x *= sc; b.y *= sc; b.z *= sc; b.w *= sc;
    *(float4*)&p[tid * 8]     = a;
    *(float4*)&p[tid * 8 + 4] = b;
}

// ---------------------------------------------------------------------------
extern "C" void kernel_launch(void* const* d_in, const int* in_sizes, int n_in,
                              void* d_out, int out_size, void* d_ws, size_t ws_size,
                              hipStream_t stream) {
    const float* x  = (const float*)d_in[0];
    const float* Wq = (const float*)d_in[1];
    // d_in[2] = Wk — unused by the reference (K = rmsnorm(V))
    const float* Wv = (const float*)d_in[3];
    const float* Wo = (const float*)d_in[4];
    float* out = (float*)d_out;

    char* ws = (char*)d_ws;
    const size_t MB = 1024 * 1024;
    unsigned short* xb  = (unsigned short*)(ws);             // 16 MB
    unsigned short* WqT = (unsigned short*)(ws + 16 * MB);   //  8 MB
    unsigned short* WoT = WqT;                               // reuse after gemm Q
    unsigned short* WvT = (unsigned short*)(ws + 24 * MB);   //  2 MB
    unsigned short* Qg  = (unsigned short*)(ws + 26 * MB);   // 16 MB
    unsigned short* Vg  = (unsigned short*)(ws + 42 * MB);   //  4 MB
    unsigned short* Kb  = (unsigned short*)(ws + 46 * MB);   //  4 MB
    unsigned short* Vt  = (unsigned short*)(ws + 50 * MB);   //  4 MB
    unsigned short* Yb  = (unsigned short*)(ws + 54 * MB);   // 16 MB  (peak 70 MB)

    const dim3 blk(256);

    cast_f16<<<2048, blk, 0, stream>>>(x, xb, MM * CC / 8);
    tcast<<<dim3(CC / 32, CC / 32), blk, 0, stream>>>(Wq, WqT, CC, CC);
    tcast<<<dim3(KVC / 32, CC / 32), blk, 0, stream>>>(Wv, WvT, CC, KVC);

    gemm_bt<1><<<dim3(CC / 128, MM / 128), blk, 0, stream>>>(xb, WqT, Qg, MM, CC, CC);
    gemm_bt<1><<<dim3(KVC / 128, MM / 128), blk, 0, stream>>>(xb, WvT, Vg, MM, KVC, CC);

    tcast<<<dim3(CC / 32, CC / 32), blk, 0, stream>>>(Wo, WoT, CC, CC);  // after gemm Q

    rms128_h<<<MM * HQ_ / 4, blk, 0, stream>>>(Qg, Qg, MM * HQ_);        // Q norm, in place
    rms128_h<<<MM * HKV_ / 4, blk, 0, stream>>>(Vg, Kb, MM * HKV_);      // K = norm(V)
    vt_build<<<dim3(TT / 32, DH / 32, BB * HKV_), blk, 0, stream>>>(Vg, Vt);

    attn_mfma<<<dim3(TT / 64, BB * HQ_), blk, 0, stream>>>(Qg, Kb, Vt, Yb);

    gemm_bt<0><<<dim3(CC / 128, MM / 128), blk, 0, stream>>>(Yb, WoT, out, MM, CC, CC);
    rms2048_inplace<<<MM, blk, 0, stream>>>(out);
}